// Round 7
// baseline (3092.576 us; speedup 1.0000x reference)
//
#include <hip/hip_runtime.h>

typedef _Float16 f16;
typedef f16 f16x8 __attribute__((ext_vector_type(8)));
typedef f16 f16x4 __attribute__((ext_vector_type(4)));
typedef float f32x4 __attribute__((ext_vector_type(4)));

#define B_ 64
#define C_ 512
#define X2D_ELEMS ((size_t)134217728)  // 64*512*64*64
#define CHAIN_PITCH 1104               // chain: [b][col][512] f16
#define CHAIN_BYTES ((size_t)B_ * CHAIN_PITCH * C_ * 2)  // 72,351,744
#define NSYNC 31

// (i,j) -> chain column, or -1 if not on any written diagonal
__device__ __forceinline__ int col_of(int i, int j) {
    const int d = j - i;
    if (d < 0) return -1;
    if (d <= 15) return 64 * d - (d * (d - 1)) / 2 + i;
    if (d >= 17 && d <= 31 && (d & 1) && !(i & 1)) {
        const int v = (d - 17) >> 1;
        return 904 + 24 * v - (v * (v - 1)) / 2 + (i >> 1);
    }
    if (d >= 35 && !((d - 35) & 3) && !(i & 3)) {
        const int v = (d - 35) >> 2;
        return 1068 + 8 * v - (v * (v - 1)) / 2 + (i >> 2);
    }
    return -1;
}

// 8-sibling barrier (blocks sharing batch b), release/acquire, device scope
__device__ __forceinline__ void bsync(int* cnt, int li, int b) {
    __syncthreads();
    if (threadIdx.x == 0) {
        int* p = cnt + li * 64 + b;
        __threadfence();
        __hip_atomic_fetch_add(p, 1, __ATOMIC_RELEASE, __HIP_MEMORY_SCOPE_AGENT);
        while (__hip_atomic_load(p, __ATOMIC_ACQUIRE, __HIP_MEMORY_SCOPE_AGENT) < 8)
            __builtin_amdgcn_s_sleep(1);
    }
    __syncthreads();
    __threadfence();
}

// stage full 512-ch input tile (Lin rows) from chain into swizzled LDS
__device__ __forceinline__
void stage_chain(f16* S, const f16* __restrict__ chin, int Lin) {
    const int lane = threadIdx.x & 63, wv = threadIdx.x >> 6;
    for (int r = wv; r < Lin; r += 4) {
        const f16x8 v = *(const f16x8*)(chin + ((size_t)r << 9) + (lane << 3));
        *(f16x8*)&S[(r << 9) + ((lane ^ (r & 7)) << 3)] = v;
    }
}

// ---------------------------------------------------------------------------
// conv slice: this block computes co in [m0, m0+64) for all output cols.
// 4 waves x 16 co each; NF col-fragments; weight ring-prefetch (4 deep).
// S: [Lin rows][512 ci], 16B-chunk XOR swizzle. Weights [co][t*512+ci] f16.
// ---------------------------------------------------------------------------
template<int K, int NF, int TAPS>
__device__ __forceinline__
void conv_split(const f16* S, const f16* __restrict__ wl,
                const float* __restrict__ bias, f16* __restrict__ chout,
                int Lin, int Lout, int m0)
{
    const int lane = threadIdx.x & 63, w = threadIdx.x >> 6;
    const int colq = lane & 15, kg = lane >> 4;
    const int mbase = m0 + w * 16;
    const f16* wp = wl + (size_t)(mbase + colq) * K + (kg << 3);

    int row[NF];
    #pragma unroll
    for (int nf = 0; nf < NF; nf++) {
        int c = nf * 16 + colq;
        if (c > Lin - TAPS) c = Lin - TAPS;   // clamp pad cols (write-masked)
        row[nf] = c;
    }

    f32x4 acc[NF] = {};
    f16x8 a0 = *(const f16x8*)(wp);
    f16x8 a1 = *(const f16x8*)(wp + 32);
    f16x8 a2 = *(const f16x8*)(wp + 64);
    f16x8 a3 = *(const f16x8*)(wp + 96);

#define DO_STEP(AF, KK)                                                         \
    {                                                                           \
        const int t_ = (TAPS == 2 && (KK) >= 512) ? 1 : 0;                      \
        const int cch_ = (((KK) & 511) >> 3) + kg;                              \
        _Pragma("unroll")                                                       \
        for (int nf = 0; nf < NF; nf++) {                                       \
            const int r_ = row[nf] + t_;                                        \
            const f16x8 bf_ = *(const f16x8*)&S[(r_ << 9) + ((cch_ ^ (r_ & 7)) << 3)]; \
            acc[nf] = __builtin_amdgcn_mfma_f32_16x16x32_f16(AF, bf_, acc[nf], 0, 0, 0); \
        }                                                                       \
    }

    #pragma unroll
    for (int k0 = 0; k0 < K; k0 += 128) {
        DO_STEP(a0, k0);      if (k0 + 128 < K) a0 = *(const f16x8*)(wp + k0 + 128);
        DO_STEP(a1, k0 + 32); if (k0 + 128 < K) a1 = *(const f16x8*)(wp + k0 + 160);
        DO_STEP(a2, k0 + 64); if (k0 + 128 < K) a2 = *(const f16x8*)(wp + k0 + 192);
        DO_STEP(a3, k0 + 96); if (k0 + 128 < K) a3 = *(const f16x8*)(wp + k0 + 224);
    }
#undef DO_STEP

    const int co0 = mbase + (kg << 2);
    const float4 bb = *(const float4*)&bias[co0];
    #pragma unroll
    for (int nf = 0; nf < NF; nf++) {
        const int col = nf * 16 + colq;
        if (col < Lout) {
            f16x4 h;
            #pragma unroll
            for (int j = 0; j < 4; j++)
                h[j] = (f16)fmaxf(acc[nf][j] + ((const float*)&bb)[j], 0.0f);
            *(f16x4*)&chout[((size_t)col << 9) + co0] = h;
        }
    }
}

// maxpool(k=3,s=2) on this block's 64-channel slice, chain -> chain
__device__ __forceinline__
void pool_split(const f16* __restrict__ chin, f16* __restrict__ chout,
                int Lp, int m0)
{
    for (int u = threadIdx.x; u < Lp * 8; u += 256) {
        const int l = u >> 3;
        const size_t off = (size_t)(m0 + ((u & 7) << 3));
        const f16x8 a = *(const f16x8*)(chin + (((size_t)(2 * l)) << 9) + off);
        const f16x8 d = *(const f16x8*)(chin + (((size_t)(2 * l + 1)) << 9) + off);
        const f16x8 e = *(const f16x8*)(chin + (((size_t)(2 * l + 2)) << 9) + off);
        f16x8 o;
        #pragma unroll
        for (int j = 0; j < 8; j++)
            o[j] = (f16)fmaxf(fmaxf((float)a[j], (float)d[j]), fmaxf((float)e[j], 0.0f));
        *(f16x8*)&chout[((size_t)l << 9) + off] = o;
    }
}

// ---------------------------------------------------------------------------
// chain kernel: 512 blocks = (b, q). Block computes co-slice [q*64, q*64+64)
// of every layer; 8 b-siblings sync via atomic counters between layers.
// ---------------------------------------------------------------------------
__global__ __launch_bounds__(256, 2)
void chain_split(const float* __restrict__ x, const f16* __restrict__ Wf,
                 const float* __restrict__ b1, const float* __restrict__ b2,
                 f16* __restrict__ chain, int* __restrict__ cnt)
{
    __shared__ __align__(16) f16 S[64 * 512];   // 64 KB
    const int tid = threadIdx.x;
    const int b = blockIdx.x >> 3, q = blockIdx.x & 7, m0 = q << 6;
    f16* chb = chain + (((size_t)b * CHAIN_PITCH) << 9);

    // stage x[b] fp32 [512 ci][64 l] -> S f16 [l][ci swizzled]
    #pragma unroll 4
    for (int p = 0; p < 32; p++) {
        const int ci = p * 16 + (tid >> 4), l0 = (tid & 15) << 2;
        const float4 v = *(const float4*)&x[(((size_t)b * C_ + ci) << 6) + l0];
        #pragma unroll
        for (int j = 0; j < 4; j++) {
            const int r = l0 + j;
            S[(r << 9) + (((ci >> 3) ^ (r & 7)) << 3) + (ci & 7)] =
                (f16)((const float*)&v)[j];
        }
    }
    __syncthreads();

    // layer 0: k=1 conv (K=512)
    conv_split<512, 4, 1>(S, Wf, b1, chb, 64, 64, m0);

    int li = 0, prev = 0, cb = 64, L = 64, k2 = 0;

    // level 0: 15 k=2 convs (64 -> 49)
    for (int i = 0; i < 15; i++) {
        bsync(cnt, li++, b);
        stage_chain(S, chb + ((size_t)prev << 9), L);
        __syncthreads();
        conv_split<1024, 4, 2>(S, Wf + 262144 + (size_t)k2 * 524288,
                               b2 + k2 * C_, chb + ((size_t)cb << 9), L, L - 1, m0);
        prev = cb; cb += L - 1; L--; k2++;
    }
    // pool (49 -> 24)
    bsync(cnt, li++, b);
    {
        const int Lp = (L - 3) / 2 + 1;
        pool_split(chb + ((size_t)prev << 9), chb + ((size_t)cb << 9), Lp, m0);
        prev = cb; cb += Lp; L = Lp;
    }
    // level 1: 7 convs (24 -> 17)
    for (int i = 0; i < 7; i++) {
        bsync(cnt, li++, b);
        stage_chain(S, chb + ((size_t)prev << 9), L);
        __syncthreads();
        conv_split<1024, 2, 2>(S, Wf + 262144 + (size_t)k2 * 524288,
                               b2 + k2 * C_, chb + ((size_t)cb << 9), L, L - 1, m0);
        prev = cb; cb += L - 1; L--; k2++;
    }
    // pool (17 -> 8)
    bsync(cnt, li++, b);
    {
        const int Lp = (L - 3) / 2 + 1;
        pool_split(chb + ((size_t)prev << 9), chb + ((size_t)cb << 9), Lp, m0);
        prev = cb; cb += Lp; L = Lp;
    }
    // level 2: 7 convs (8 -> 1)
    for (int i = 0; i < 7; i++) {
        bsync(cnt, li++, b);
        stage_chain(S, chb + ((size_t)prev << 9), L);
        __syncthreads();
        conv_split<1024, 1, 2>(S, Wf + 262144 + (size_t)k2 * 524288,
                               b2 + k2 * C_, chb + ((size_t)cb << 9), L, L - 1, m0);
        prev = cb; cb += L - 1; L--; k2++;
    }
}

// prep: mask + zero sync counters + weights fp32 -> f16 [co][t*512+ci]
__global__ void prep_k(const float* __restrict__ w1, const float* __restrict__ w2,
                       f16* __restrict__ Wf, float* __restrict__ maskp,
                       int* __restrict__ cnt)
{
    const unsigned idx = blockIdx.x * 256 + threadIdx.x;
    if (idx < 4096u)
        maskp[idx] = (col_of(idx >> 6, idx & 63) >= 0) ? 1.0f : 0.0f;
    if (idx < NSYNC * 64u) cnt[idx] = 0;
    if (idx < 262144u) {
        Wf[idx] = (f16)w1[idx];
    } else if (idx < 30u * 262144u) {
        const unsigned r = idx - 262144u;
        const int k2 = r >> 18;
        const unsigned rem = r & 262143u;
        const int co = rem >> 9, ci = rem & 511;
        const float2 v = *(const float2*)&w2[((((size_t)k2 << 9) + co) << 10) + (ci << 1)];
        f16* base = Wf + 262144 + ((size_t)k2 << 19) + ((size_t)co << 10);
        base[ci] = (f16)v.x;
        base[512 + ci] = (f16)v.y;
    }
}

// assemble (R4-proven): block=(i, b); stage 64 j-rows swizzled; coalesced write
__global__ __launch_bounds__(256)
void assemble_k(const f16* __restrict__ chain, float* __restrict__ x2d)
{
    __shared__ __align__(16) f16 S[64 * 512];
    const int tid = threadIdx.x, lane = tid & 63, wv = tid >> 6;
    const int i = blockIdx.x, b = blockIdx.y;

    for (int j = wv; j < 64; j += 4) {
        const int col = col_of(i, j);
        f16x8 v = {0, 0, 0, 0, 0, 0, 0, 0};
        if (col >= 0)
            v = *(const f16x8*)(chain + (((size_t)b * CHAIN_PITCH + col) << 9) + (lane << 3));
        *(f16x8*)&S[(j << 9) + ((lane ^ (j & 7)) << 3)] = v;
    }
    __syncthreads();
    const int jq = tid & 15, c0 = tid >> 4;
    float* dst0 = x2d + (((size_t)b * C_) << 12) + (i << 6) + (jq << 2);
    for (int ct = 0; ct < 32; ct++) {
        const int c = c0 + (ct << 4);
        const int cj = c >> 3;
        float4 o;
        #pragma unroll
        for (int jj = 0; jj < 4; jj++) {
            const int j = (jq << 2) + jj;
            ((float*)&o)[jj] = (float)S[(j << 9) + ((cj ^ (j & 7)) << 3) + (c & 7)];
        }
        *(float4*)(dst0 + ((size_t)c << 12)) = o;
    }
}

extern "C" void kernel_launch(void* const* d_in, const int* in_sizes, int n_in,
                              void* d_out, int out_size, void* d_ws, size_t ws_size,
                              hipStream_t stream)
{
    const float* x  = (const float*)d_in[0];
    const float* w1 = (const float*)d_in[1];
    const float* b1 = (const float*)d_in[2];
    const float* w2 = (const float*)d_in[3];
    const float* b2 = (const float*)d_in[4];
    float* x2d   = (float*)d_out;
    float* maskp = x2d + X2D_ELEMS;

    // chain (72.3 MB) + sync counters in d_ws; f16 weights (31 MB) in the
    // x2d region — fully overwritten by assemble_k afterwards.
    f16* chain = (f16*)d_ws;
    int* cnt   = (int*)((char*)d_ws + CHAIN_BYTES);
    f16* Wf    = (f16*)x2d;

    prep_k<<<(30 * 262144) / 256, 256, 0, stream>>>(w1, w2, Wf, maskp, cnt);
    chain_split<<<512, 256, 0, stream>>>(x, Wf, b1, b2, chain, cnt);
    assemble_k<<<dim3(64, B_), 256, 0, stream>>>(chain, x2d);
}

// Round 8
// 901.764 us; speedup vs baseline: 3.4295x; 3.4295x over previous
//
#include <hip/hip_runtime.h>

typedef _Float16 f16;
typedef f16 f16x8 __attribute__((ext_vector_type(8)));
typedef f16 f16x4 __attribute__((ext_vector_type(4)));
typedef float f32x4 __attribute__((ext_vector_type(4)));

#define B_ 64
#define C_ 512
#define X2D_ELEMS ((size_t)134217728)  // 64*512*64*64
#define CHAIN_PITCH 1104               // chain: [b][col][512] f16

// (i,j) -> chain column, or -1
__device__ __forceinline__ int col_of(int i, int j) {
    const int d = j - i;
    if (d < 0) return -1;
    if (d <= 15) return 64 * d - (d * (d - 1)) / 2 + i;
    if (d >= 17 && d <= 31 && (d & 1) && !(i & 1)) {
        const int v = (d - 17) >> 1;
        return 904 + 24 * v - (v * (v - 1)) / 2 + (i >> 1);
    }
    if (d >= 35 && !((d - 35) & 3) && !(i & 3)) {
        const int v = (d - 35) >> 2;
        return 1068 + 8 * v - (v * (v - 1)) / 2 + (i >> 2);
    }
    return -1;
}

// stage Lin chain cols (full 512 ch) into chunk-XOR-swizzled LDS
__device__ __forceinline__
void stage_chain(f16* S, const f16* __restrict__ chin, int Lin) {
    const int lane = threadIdx.x & 63, wv = threadIdx.x >> 6;
    for (int r = wv; r < Lin; r += 4) {
        const f16x8 v = *(const f16x8*)(chin + ((size_t)r << 9) + (lane << 3));
        *(f16x8*)&S[(r << 9) + ((lane ^ (r & 7)) << 3)] = v;
    }
}

// ---------------------------------------------------------------------------
// co-sliced conv (R7-verified): block computes co [m0,m0+64) x all cols.
// Barrier-free K loop, 4-deep weight ring prefetch. S swizzled [rows][512].
// ---------------------------------------------------------------------------
template<int K, int NF, int TAPS>
__device__ __forceinline__
void conv_split(const f16* S, const f16* __restrict__ wl,
                const float* __restrict__ bias, f16* __restrict__ chout,
                int Lin, int Lout, int m0)
{
    const int lane = threadIdx.x & 63, w = threadIdx.x >> 6;
    const int colq = lane & 15, kg = lane >> 4;
    const int mbase = m0 + w * 16;
    const f16* wp = wl + (size_t)(mbase + colq) * K + (kg << 3);

    int row[NF];
    #pragma unroll
    for (int nf = 0; nf < NF; nf++) {
        int c = nf * 16 + colq;
        if (c > Lin - TAPS) c = Lin - TAPS;
        row[nf] = c;
    }

    f32x4 acc[NF] = {};
    f16x8 a0 = *(const f16x8*)(wp);
    f16x8 a1 = *(const f16x8*)(wp + 32);
    f16x8 a2 = *(const f16x8*)(wp + 64);
    f16x8 a3 = *(const f16x8*)(wp + 96);

#define DO_STEP(AF, KK)                                                         \
    {                                                                           \
        const int t_ = (TAPS == 2 && (KK) >= 512) ? 1 : 0;                      \
        const int cch_ = (((KK) & 511) >> 3) + kg;                              \
        _Pragma("unroll")                                                       \
        for (int nf = 0; nf < NF; nf++) {                                       \
            const int r_ = row[nf] + t_;                                        \
            const f16x8 bf_ = *(const f16x8*)&S[(r_ << 9) + ((cch_ ^ (r_ & 7)) << 3)]; \
            acc[nf] = __builtin_amdgcn_mfma_f32_16x16x32_f16(AF, bf_, acc[nf], 0, 0, 0); \
        }                                                                       \
    }

    #pragma unroll
    for (int k0 = 0; k0 < K; k0 += 128) {
        DO_STEP(a0, k0);      if (k0 + 128 < K) a0 = *(const f16x8*)(wp + k0 + 128);
        DO_STEP(a1, k0 + 32); if (k0 + 128 < K) a1 = *(const f16x8*)(wp + k0 + 160);
        DO_STEP(a2, k0 + 64); if (k0 + 128 < K) a2 = *(const f16x8*)(wp + k0 + 192);
        DO_STEP(a3, k0 + 96); if (k0 + 128 < K) a3 = *(const f16x8*)(wp + k0 + 224);
    }
#undef DO_STEP

    const int co0 = mbase + (kg << 2);
    const float4 bb = *(const float4*)&bias[co0];
    #pragma unroll
    for (int nf = 0; nf < NF; nf++) {
        const int col = nf * 16 + colq;
        if (col < Lout) {
            f16x4 h;
            #pragma unroll
            for (int j = 0; j < 4; j++)
                h[j] = (f16)fmaxf(acc[nf][j] + ((const float*)&bb)[j], 0.0f);
            *(f16x4*)&chout[((size_t)col << 9) + co0] = h;
        }
    }
}

// ---------------------------------------------------------------------------
// full-co conv (R6-verified): 4 waves x 128 co, LDS->LDS + chain write.
// ---------------------------------------------------------------------------
template<int K, int NF, int TAPS>
__device__ __forceinline__
void conv_step(const f16* Scur, f16* Snxt,
               const f16* __restrict__ wl, const float* __restrict__ bias,
               f16* __restrict__ chout, int Lin, int Lout)
{
    const int tid = threadIdx.x, lane = tid & 63, w = tid >> 6;
    const int colq = lane & 15, kg = lane >> 4;
    const f16* wp = wl + (size_t)(w * 128 + colq) * K + (kg << 3);

    int row[NF];
    #pragma unroll
    for (int nf = 0; nf < NF; nf++) {
        int c = nf * 16 + colq;
        if (TAPS == 2 && c > Lin - 2) c = Lin - 2;
        row[nf] = c;
    }

    f32x4 acc[8][NF] = {};
    f16x8 afA[8], afB[8];
    #pragma unroll
    for (int m = 0; m < 8; m++) afA[m] = *(const f16x8*)(wp + (m << 4) * K);

    for (int k0 = 0; k0 < K; k0 += 64) {
        #pragma unroll
        for (int m = 0; m < 8; m++)
            afB[m] = *(const f16x8*)(wp + (m << 4) * K + k0 + 32);
        {
            const int t = (TAPS == 2 && k0 >= 512) ? 1 : 0;
            const int cch = ((k0 & 511) >> 3) + kg;
            f16x8 bf[NF];
            #pragma unroll
            for (int nf = 0; nf < NF; nf++) {
                const int r = row[nf] + t;
                bf[nf] = *(const f16x8*)&Scur[(r << 9) + ((cch ^ (r & 7)) << 3)];
            }
            #pragma unroll
            for (int m = 0; m < 8; m++)
                #pragma unroll
                for (int nf = 0; nf < NF; nf++)
                    acc[m][nf] = __builtin_amdgcn_mfma_f32_16x16x32_f16(
                        afA[m], bf[nf], acc[m][nf], 0, 0, 0);
        }
        if (k0 + 64 < K) {
            #pragma unroll
            for (int m = 0; m < 8; m++)
                afA[m] = *(const f16x8*)(wp + (m << 4) * K + k0 + 64);
        }
        {
            const int k1 = k0 + 32;
            const int t = (TAPS == 2 && k1 >= 512) ? 1 : 0;
            const int cch = ((k1 & 511) >> 3) + kg;
            f16x8 bf[NF];
            #pragma unroll
            for (int nf = 0; nf < NF; nf++) {
                const int r = row[nf] + t;
                bf[nf] = *(const f16x8*)&Scur[(r << 9) + ((cch ^ (r & 7)) << 3)];
            }
            #pragma unroll
            for (int m = 0; m < 8; m++)
                #pragma unroll
                for (int nf = 0; nf < NF; nf++)
                    acc[m][nf] = __builtin_amdgcn_mfma_f32_16x16x32_f16(
                        afB[m], bf[nf], acc[m][nf], 0, 0, 0);
        }
    }

    #pragma unroll
    for (int m = 0; m < 8; m++) {
        const int co = w * 128 + (m << 4) + (kg << 2);
        const float4 bb = *(const float4*)&bias[co];
        #pragma unroll
        for (int nf = 0; nf < NF; nf++) {
            const int col = nf * 16 + colq;
            if (col < Lout) {
                f16x4 h;
                #pragma unroll
                for (int j = 0; j < 4; j++)
                    h[j] = (f16)fmaxf(acc[m][nf][j] + ((const float*)&bb)[j], 0.0f);
                *(f16x4*)&Snxt[(col << 9) + ((((co >> 3) ^ (col & 7)) << 3) + (co & 7))] = h;
                *(f16x4*)&chout[((size_t)col << 9) + co] = h;
            }
        }
    }
}

// maxpool(k=3,s=2), LDS->LDS swizzled + chain write (R6-verified)
__device__ __forceinline__
void pool_step(const f16* Scur, f16* Snxt, f16* __restrict__ chout, int Lp)
{
    for (int u = threadIdx.x; u < Lp * 64; u += 256) {
        const int l = u >> 6, c8 = u & 63;
        const int r0 = 2 * l, r1 = r0 + 1, r2 = r0 + 2;
        const f16x8 a = *(const f16x8*)&Scur[(r0 << 9) + ((c8 ^ (r0 & 7)) << 3)];
        const f16x8 d = *(const f16x8*)&Scur[(r1 << 9) + ((c8 ^ (r1 & 7)) << 3)];
        const f16x8 e = *(const f16x8*)&Scur[(r2 << 9) + ((c8 ^ (r2 & 7)) << 3)];
        f16x8 o;
        #pragma unroll
        for (int j = 0; j < 8; j++)
            o[j] = (f16)fmaxf(fmaxf((float)a[j], (float)d[j]), fmaxf((float)e[j], 0.0f));
        *(f16x8*)&Snxt[(l << 9) + ((c8 ^ (l & 7)) << 3)] = o;
        *(f16x8*)&chout[((size_t)l << 9) + (c8 << 3)] = o;
    }
}

// ---- level-0 per-layer kernels: grid 512 = (b, q co-slice), no inner barriers
__global__ __launch_bounds__(256, 2)
void conv_l0_first(const float* __restrict__ x, const f16* __restrict__ Wf,
                   const float* __restrict__ b1, f16* __restrict__ chain)
{
    __shared__ __align__(16) f16 S[64 * 512];
    const int tid = threadIdx.x;
    const int b = blockIdx.x >> 3, q = blockIdx.x & 7;
    f16* chb = chain + (((size_t)b * CHAIN_PITCH) << 9);
    #pragma unroll 4
    for (int p = 0; p < 32; p++) {
        const int ci = p * 16 + (tid >> 4), l0 = (tid & 15) << 2;
        const float4 v = *(const float4*)&x[(((size_t)b * C_ + ci) << 6) + l0];
        #pragma unroll
        for (int j = 0; j < 4; j++) {
            const int r = l0 + j;
            S[(r << 9) + (((ci >> 3) ^ (r & 7)) << 3) + (ci & 7)] =
                (f16)((const float*)&v)[j];
        }
    }
    __syncthreads();
    conv_split<512, 4, 1>(S, Wf, b1, chb, 64, 64, q << 6);
}

__global__ __launch_bounds__(256, 2)
void conv_l0(const f16* __restrict__ Wl, const float* __restrict__ bias,
             f16* __restrict__ chain, int cb_in, int cb_out, int Lin)
{
    __shared__ __align__(16) f16 S[64 * 512];
    const int b = blockIdx.x >> 3, q = blockIdx.x & 7;
    f16* chb = chain + (((size_t)b * CHAIN_PITCH) << 9);
    stage_chain(S, chb + ((size_t)cb_in << 9), Lin);
    __syncthreads();
    conv_split<1024, 4, 2>(S, Wl, bias, chb + ((size_t)cb_out << 9), Lin, Lin - 1, q << 6);
}

// ---- fused level kernel: 64 blocks (one per b): pool + NCONV convs in LDS
template<int NCONV, int NF>
__global__ __launch_bounds__(256, 1)
void level_fused(const f16* __restrict__ Wf2, const float* __restrict__ b2s,
                 f16* __restrict__ chain, int cb_in, int Lin, int cb0)
{
    __shared__ __align__(16) f16 Sin[49 * 512];
    __shared__ __align__(16) f16 Sa[24 * 512];
    __shared__ __align__(16) f16 Sb[24 * 512];
    const int b = blockIdx.x;
    f16* chb = chain + (((size_t)b * CHAIN_PITCH) << 9);

    stage_chain(Sin, chb + ((size_t)cb_in << 9), Lin);
    __syncthreads();

    const int Lp = (Lin - 3) / 2 + 1;
    pool_step(Sin, Sa, chb + ((size_t)cb0 << 9), Lp);
    __syncthreads();

    int L = Lp, cb = cb0 + Lp;
    f16* cur = Sa; f16* nxt = Sb;
    #pragma unroll 1
    for (int i = 0; i < NCONV; i++) {
        conv_step<1024, NF, 2>(cur, nxt, Wf2 + (size_t)i * 524288, b2s + i * C_,
                               chb + ((size_t)cb << 9), L, L - 1);
        __syncthreads();
        f16* t = cur; cur = nxt; nxt = t;
        cb += L - 1; L--;
    }
}

// prep: mask + weights fp32 -> f16 [co][t*512+ci]
__global__ void prep_k(const float* __restrict__ w1, const float* __restrict__ w2,
                       f16* __restrict__ Wf, float* __restrict__ maskp)
{
    const unsigned idx = blockIdx.x * 256 + threadIdx.x;
    if (idx < 4096u)
        maskp[idx] = (col_of(idx >> 6, idx & 63) >= 0) ? 1.0f : 0.0f;
    if (idx < 262144u) {
        Wf[idx] = (f16)w1[idx];
    } else if (idx < 30u * 262144u) {
        const unsigned r = idx - 262144u;
        const int k2 = r >> 18;
        const unsigned rem = r & 262143u;
        const int co = rem >> 9, ci = rem & 511;
        const float2 v = *(const float2*)&w2[((((size_t)k2 << 9) + co) << 10) + (ci << 1)];
        f16* base = Wf + 262144 + ((size_t)k2 << 19) + ((size_t)co << 10);
        base[ci] = (f16)v.x;
        base[512 + ci] = (f16)v.y;
    }
}

// assemble (verified): block=(i, b); swizzled LDS stage; coalesced x2d write
__global__ __launch_bounds__(256)
void assemble_k(const f16* __restrict__ chain, float* __restrict__ x2d)
{
    __shared__ __align__(16) f16 S[64 * 512];
    const int tid = threadIdx.x, lane = tid & 63, wv = tid >> 6;
    const int i = blockIdx.x, b = blockIdx.y;

    for (int j = wv; j < 64; j += 4) {
        const int col = col_of(i, j);
        f16x8 v = {0, 0, 0, 0, 0, 0, 0, 0};
        if (col >= 0)
            v = *(const f16x8*)(chain + (((size_t)b * CHAIN_PITCH + col) << 9) + (lane << 3));
        *(f16x8*)&S[(j << 9) + ((lane ^ (j & 7)) << 3)] = v;
    }
    __syncthreads();
    const int jq = tid & 15, c0 = tid >> 4;
    float* dst0 = x2d + (((size_t)b * C_) << 12) + (i << 6) + (jq << 2);
    for (int ct = 0; ct < 32; ct++) {
        const int c = c0 + (ct << 4);
        const int cj = c >> 3;
        float4 o;
        #pragma unroll
        for (int jj = 0; jj < 4; jj++) {
            const int j = (jq << 2) + jj;
            ((float*)&o)[jj] = (float)S[(j << 9) + ((cj ^ (j & 7)) << 3) + (c & 7)];
        }
        *(float4*)(dst0 + ((size_t)c << 12)) = o;
    }
}

extern "C" void kernel_launch(void* const* d_in, const int* in_sizes, int n_in,
                              void* d_out, int out_size, void* d_ws, size_t ws_size,
                              hipStream_t stream)
{
    const float* x  = (const float*)d_in[0];
    const float* w1 = (const float*)d_in[1];
    const float* b1 = (const float*)d_in[2];
    const float* w2 = (const float*)d_in[3];
    const float* b2 = (const float*)d_in[4];
    float* x2d   = (float*)d_out;
    float* maskp = x2d + X2D_ELEMS;

    f16* chain = (f16*)d_ws;     // 72.3 MB
    f16* Wf    = (f16*)x2d;      // 31 MB scratch in x2d region, dead before assemble

    prep_k<<<(30 * 262144) / 256, 256, 0, stream>>>(w1, w2, Wf, maskp);

    // level 0: 16 per-layer kernels (co-split, barrier-free inner loop)
    conv_l0_first<<<512, 256, 0, stream>>>(x, Wf, b1, chain);
    int L = 64, cb = 64, prev = 0;
    for (int i = 0; i < 15; i++) {
        conv_l0<<<512, 256, 0, stream>>>(Wf + 262144 + (size_t)i * 524288,
                                         b2 + (size_t)i * C_, chain, prev, cb, L);
        prev = cb; cb += L - 1; L--;
    }
    // now L=49, prev=855, cb=904

    // level 1: pool(49->24) + 7 convs, one kernel
    level_fused<7, 2><<<64, 256, 0, stream>>>(
        Wf + 262144 + (size_t)15 * 524288, b2 + (size_t)15 * C_, chain, 855, 49, 904);
    // level 2: pool(17->8) + 7 convs, one kernel
    level_fused<7, 1><<<64, 256, 0, stream>>>(
        Wf + 262144 + (size_t)22 * 524288, b2 + (size_t)22 * C_, chain, 1051, 17, 1068);

    assemble_k<<<dim3(64, B_), 256, 0, stream>>>(chain, x2d);
}

// Round 9
// 874.125 us; speedup vs baseline: 3.5379x; 1.0316x over previous
//
#include <hip/hip_runtime.h>

typedef _Float16 f16;
typedef f16 f16x8 __attribute__((ext_vector_type(8)));
typedef f16 f16x4 __attribute__((ext_vector_type(4)));
typedef float f32x4 __attribute__((ext_vector_type(4)));

#define B_ 64
#define C_ 512
#define X2D_ELEMS ((size_t)134217728)  // 64*512*64*64
#define CHAIN_PITCH 1104               // chain: [b][col][512] f16

#define GLOBAL_AS __attribute__((address_space(1)))
#define LDS_AS    __attribute__((address_space(3)))

// async 16B/lane global->LDS (dest = wave-uniform base + lane*16)
__device__ __forceinline__
void gload_lds16(const void* g, void* l) {
    __builtin_amdgcn_global_load_lds((const GLOBAL_AS void*)g, (LDS_AS void*)l,
                                     16, 0, 0);
}

// (i,j) -> chain column, or -1
__device__ __forceinline__ int col_of(int i, int j) {
    const int d = j - i;
    if (d < 0) return -1;
    if (d <= 15) return 64 * d - (d * (d - 1)) / 2 + i;
    if (d >= 17 && d <= 31 && (d & 1) && !(i & 1)) {
        const int v = (d - 17) >> 1;
        return 904 + 24 * v - (v * (v - 1)) / 2 + (i >> 1);
    }
    if (d >= 35 && !((d - 35) & 3) && !(i & 3)) {
        const int v = (d - 35) >> 2;
        return 1068 + 8 * v - (v * (v - 1)) / 2 + (i >> 2);
    }
    return -1;
}

// stage LIN chain cols (1 KB each) into chunk-XOR-swizzled LDS via
// global_load_lds: linear LDS dest + inverse-swizzled global source.
template<int LIN, int WAVES>
__device__ __forceinline__
void stage_rows(f16* S, const f16* __restrict__ chin) {
    const int lane = threadIdx.x & 63, wv = threadIdx.x >> 6;
    #pragma unroll
    for (int it = 0; it < (LIN + WAVES - 1) / WAVES; ++it) {
        const int r = wv + it * WAVES;           // wave-uniform
        if (r < LIN)
            gload_lds16(chin + ((size_t)r << 9) + ((lane ^ (r & 7)) << 3),
                        &S[r << 9]);
    }
}

// ---------------------------------------------------------------------------
// co-sliced conv (R7/R8-verified): block computes co [m0,m0+64) x all cols.
// Barrier-free K loop, 4-deep weight ring prefetch. S swizzled [rows][512].
// ---------------------------------------------------------------------------
template<int K, int NF, int TAPS>
__device__ __forceinline__
void conv_split(const f16* S, const f16* __restrict__ wl,
                const float* __restrict__ bias, f16* __restrict__ chout,
                int Lin, int Lout, int m0)
{
    const int lane = threadIdx.x & 63, w = threadIdx.x >> 6;
    const int colq = lane & 15, kg = lane >> 4;
    const int mbase = m0 + w * 16;
    const f16* wp = wl + (size_t)(mbase + colq) * K + (kg << 3);

    int row[NF];
    #pragma unroll
    for (int nf = 0; nf < NF; nf++) {
        int c = nf * 16 + colq;
        if (c > Lin - TAPS) c = Lin - TAPS;
        row[nf] = c;
    }

    f32x4 acc[NF] = {};
    f16x8 a0 = *(const f16x8*)(wp);
    f16x8 a1 = *(const f16x8*)(wp + 32);
    f16x8 a2 = *(const f16x8*)(wp + 64);
    f16x8 a3 = *(const f16x8*)(wp + 96);

#define DO_STEP(AF, KK)                                                         \
    {                                                                           \
        const int t_ = (TAPS == 2 && (KK) >= 512) ? 1 : 0;                      \
        const int cch_ = (((KK) & 511) >> 3) + kg;                              \
        _Pragma("unroll")                                                       \
        for (int nf = 0; nf < NF; nf++) {                                       \
            const int r_ = row[nf] + t_;                                        \
            const f16x8 bf_ = *(const f16x8*)&S[(r_ << 9) + ((cch_ ^ (r_ & 7)) << 3)]; \
            acc[nf] = __builtin_amdgcn_mfma_f32_16x16x32_f16(AF, bf_, acc[nf], 0, 0, 0); \
        }                                                                       \
    }

    #pragma unroll
    for (int k0 = 0; k0 < K; k0 += 128) {
        DO_STEP(a0, k0);      if (k0 + 128 < K) a0 = *(const f16x8*)(wp + k0 + 128);
        DO_STEP(a1, k0 + 32); if (k0 + 128 < K) a1 = *(const f16x8*)(wp + k0 + 160);
        DO_STEP(a2, k0 + 64); if (k0 + 128 < K) a2 = *(const f16x8*)(wp + k0 + 192);
        DO_STEP(a3, k0 + 96); if (k0 + 128 < K) a3 = *(const f16x8*)(wp + k0 + 224);
    }
#undef DO_STEP

    const int co0 = mbase + (kg << 2);
    const float4 bb = *(const float4*)&bias[co0];
    #pragma unroll
    for (int nf = 0; nf < NF; nf++) {
        const int col = nf * 16 + colq;
        if (col < Lout) {
            f16x4 h;
            #pragma unroll
            for (int j = 0; j < 4; j++)
                h[j] = (f16)fmaxf(acc[nf][j] + ((const float*)&bb)[j], 0.0f);
            *(f16x4*)&chout[((size_t)col << 9) + co0] = h;
        }
    }
}

// ---------------------------------------------------------------------------
// 8-wave full-co conv for the fused level kernels: wave w owns co
// [w*64, w*64+64), m-loop 4, double-buffered weight prefetch.
// ---------------------------------------------------------------------------
template<int K, int NF, int TAPS>
__device__ __forceinline__
void conv_step8(const f16* Scur, f16* Snxt,
                const f16* __restrict__ wl, const float* __restrict__ bias,
                f16* __restrict__ chout, int Lin, int Lout)
{
    const int tid = threadIdx.x, lane = tid & 63, w = tid >> 6;  // 0..7
    const int colq = lane & 15, kg = lane >> 4;
    const f16* wp = wl + (size_t)(w * 64 + colq) * K + (kg << 3);

    int row[NF];
    #pragma unroll
    for (int nf = 0; nf < NF; nf++) {
        int c = nf * 16 + colq;
        if (c > Lin - TAPS) c = Lin - TAPS;
        row[nf] = c;
    }

    f32x4 acc[4][NF] = {};
    f16x8 afA[4], afB[4];
    #pragma unroll
    for (int m = 0; m < 4; m++) afA[m] = *(const f16x8*)(wp + (m << 4) * K);

    for (int k0 = 0; k0 < K; k0 += 64) {
        #pragma unroll
        for (int m = 0; m < 4; m++)
            afB[m] = *(const f16x8*)(wp + (m << 4) * K + k0 + 32);
        {   // k = k0
            const int t = (TAPS == 2 && k0 >= 512) ? 1 : 0;
            const int cch = ((k0 & 511) >> 3) + kg;
            f16x8 bf[NF];
            #pragma unroll
            for (int nf = 0; nf < NF; nf++) {
                const int r = row[nf] + t;
                bf[nf] = *(const f16x8*)&Scur[(r << 9) + ((cch ^ (r & 7)) << 3)];
            }
            #pragma unroll
            for (int m = 0; m < 4; m++)
                #pragma unroll
                for (int nf = 0; nf < NF; nf++)
                    acc[m][nf] = __builtin_amdgcn_mfma_f32_16x16x32_f16(
                        afA[m], bf[nf], acc[m][nf], 0, 0, 0);
        }
        if (k0 + 64 < K) {
            #pragma unroll
            for (int m = 0; m < 4; m++)
                afA[m] = *(const f16x8*)(wp + (m << 4) * K + k0 + 64);
        }
        {   // k = k0 + 32
            const int k1 = k0 + 32;
            const int t = (TAPS == 2 && k1 >= 512) ? 1 : 0;
            const int cch = ((k1 & 511) >> 3) + kg;
            f16x8 bf[NF];
            #pragma unroll
            for (int nf = 0; nf < NF; nf++) {
                const int r = row[nf] + t;
                bf[nf] = *(const f16x8*)&Scur[(r << 9) + ((cch ^ (r & 7)) << 3)];
            }
            #pragma unroll
            for (int m = 0; m < 4; m++)
                #pragma unroll
                for (int nf = 0; nf < NF; nf++)
                    acc[m][nf] = __builtin_amdgcn_mfma_f32_16x16x32_f16(
                        afB[m], bf[nf], acc[m][nf], 0, 0, 0);
        }
    }

    #pragma unroll
    for (int m = 0; m < 4; m++) {
        const int co = w * 64 + (m << 4) + (kg << 2);
        const float4 bb = *(const float4*)&bias[co];
        #pragma unroll
        for (int nf = 0; nf < NF; nf++) {
            const int col = nf * 16 + colq;
            if (col < Lout) {
                f16x4 h;
                #pragma unroll
                for (int j = 0; j < 4; j++)
                    h[j] = (f16)fmaxf(acc[m][nf][j] + ((const float*)&bb)[j], 0.0f);
                *(f16x4*)&Snxt[(col << 9) + ((((co >> 3) ^ (col & 7)) << 3) + (co & 7))] = h;
                *(f16x4*)&chout[((size_t)col << 9) + co] = h;
            }
        }
    }
}

// maxpool(k=3,s=2), LDS->LDS swizzled + chain write (512 threads)
__device__ __forceinline__
void pool_step(const f16* Scur, f16* Snxt, f16* __restrict__ chout, int Lp)
{
    for (int u = threadIdx.x; u < Lp * 64; u += 512) {
        const int l = u >> 6, c8 = u & 63;
        const int r0 = 2 * l, r1 = r0 + 1, r2 = r0 + 2;
        const f16x8 a = *(const f16x8*)&Scur[(r0 << 9) + ((c8 ^ (r0 & 7)) << 3)];
        const f16x8 d = *(const f16x8*)&Scur[(r1 << 9) + ((c8 ^ (r1 & 7)) << 3)];
        const f16x8 e = *(const f16x8*)&Scur[(r2 << 9) + ((c8 ^ (r2 & 7)) << 3)];
        f16x8 o;
        #pragma unroll
        for (int j = 0; j < 8; j++)
            o[j] = (f16)fmaxf(fmaxf((float)a[j], (float)d[j]), fmaxf((float)e[j], 0.0f));
        *(f16x8*)&Snxt[(l << 9) + ((c8 ^ (l & 7)) << 3)] = o;
        *(f16x8*)&chout[((size_t)l << 9) + (c8 << 3)] = o;
    }
}

// ---- level-0 kernels: grid 512 = (b, q co-slice), barrier-free inner loop
__global__ __launch_bounds__(256, 2)
void conv_l0_first(const float* __restrict__ x, const f16* __restrict__ Wf,
                   const float* __restrict__ b1, f16* __restrict__ chain)
{
    __shared__ __align__(16) f16 S[64 * 512];
    const int tid = threadIdx.x;
    const int b = blockIdx.x >> 3, q = blockIdx.x & 7;
    f16* chb = chain + (((size_t)b * CHAIN_PITCH) << 9);
    #pragma unroll 4
    for (int p = 0; p < 32; p++) {
        const int ci = p * 16 + (tid >> 4), l0 = (tid & 15) << 2;
        const float4 v = *(const float4*)&x[(((size_t)b * C_ + ci) << 6) + l0];
        #pragma unroll
        for (int j = 0; j < 4; j++) {
            const int r = l0 + j;
            S[(r << 9) + (((ci >> 3) ^ (r & 7)) << 3) + (ci & 7)] =
                (f16)((const float*)&v)[j];
        }
    }
    __syncthreads();
    conv_split<512, 4, 1>(S, Wf, b1, chb, 64, 64, q << 6);
}

template<int LIN>
__global__ __launch_bounds__(256, 2)
void conv_l0(const f16* __restrict__ Wl, const float* __restrict__ bias,
             f16* __restrict__ chain, int cb_in, int cb_out)
{
    __shared__ __align__(16) f16 S[64 * 512];
    const int b = blockIdx.x >> 3, q = blockIdx.x & 7;
    f16* chb = chain + (((size_t)b * CHAIN_PITCH) << 9);
    stage_rows<LIN, 4>(S, chb + ((size_t)cb_in << 9));
    __syncthreads();
    conv_split<1024, 4, 2>(S, Wl, bias, chb + ((size_t)cb_out << 9), LIN, LIN - 1, q << 6);
}

// ---- fused level kernel: 64 blocks x 512 threads: pool + NCONV convs in LDS
template<int LIN, int NCONV, int NF>
__global__ __launch_bounds__(512, 1)
void level_fused(const f16* __restrict__ Wf2, const float* __restrict__ b2s,
                 f16* __restrict__ chain, int cb_in, int cb0)
{
    constexpr int LP = (LIN - 3) / 2 + 1;
    __shared__ __align__(16) f16 Sin[LIN * 512];
    __shared__ __align__(16) f16 Sa[LP * 512];
    __shared__ __align__(16) f16 Sb[LP * 512];
    const int b = blockIdx.x;
    f16* chb = chain + (((size_t)b * CHAIN_PITCH) << 9);

    stage_rows<LIN, 8>(Sin, chb + ((size_t)cb_in << 9));
    __syncthreads();

    pool_step(Sin, Sa, chb + ((size_t)cb0 << 9), LP);
    __syncthreads();

    int L = LP, cb = cb0 + LP;
    f16* cur = Sa; f16* nxt = Sb;
    #pragma unroll 1
    for (int i = 0; i < NCONV; i++) {
        conv_step8<1024, NF, 2>(cur, nxt, Wf2 + (size_t)i * 524288, b2s + i * C_,
                                chb + ((size_t)cb << 9), L, L - 1);
        __syncthreads();
        f16* t = cur; cur = nxt; nxt = t;
        cb += L - 1; L--;
    }
}

// prep: mask + weights fp32 -> f16 [co][t*512+ci]
__global__ void prep_k(const float* __restrict__ w1, const float* __restrict__ w2,
                       f16* __restrict__ Wf, float* __restrict__ maskp)
{
    const unsigned idx = blockIdx.x * 256 + threadIdx.x;
    if (idx < 4096u)
        maskp[idx] = (col_of(idx >> 6, idx & 63) >= 0) ? 1.0f : 0.0f;
    if (idx < 262144u) {
        Wf[idx] = (f16)w1[idx];
    } else if (idx < 30u * 262144u) {
        const unsigned r = idx - 262144u;
        const int k2 = r >> 18;
        const unsigned rem = r & 262143u;
        const int co = rem >> 9, ci = rem & 511;
        const float2 v = *(const float2*)&w2[((((size_t)k2 << 9) + co) << 10) + (ci << 1)];
        f16* base = Wf + 262144 + ((size_t)k2 << 19) + ((size_t)co << 10);
        base[ci] = (f16)v.x;
        base[512 + ci] = (f16)v.y;
    }
}

// assemble (verified): block=(i, b); swizzled LDS stage; coalesced x2d write
__global__ __launch_bounds__(256)
void assemble_k(const f16* __restrict__ chain, float* __restrict__ x2d)
{
    __shared__ __align__(16) f16 S[64 * 512];
    const int tid = threadIdx.x, lane = tid & 63, wv = tid >> 6;
    const int i = blockIdx.x, b = blockIdx.y;

    for (int j = wv; j < 64; j += 4) {
        const int col = col_of(i, j);
        f16x8 v = {0, 0, 0, 0, 0, 0, 0, 0};
        if (col >= 0)
            v = *(const f16x8*)(chain + (((size_t)b * CHAIN_PITCH + col) << 9) + (lane << 3));
        *(f16x8*)&S[(j << 9) + ((lane ^ (j & 7)) << 3)] = v;
    }
    __syncthreads();
    const int jq = tid & 15, c0 = tid >> 4;
    float* dst0 = x2d + (((size_t)b * C_) << 12) + (i << 6) + (jq << 2);
    for (int ct = 0; ct < 32; ct++) {
        const int c = c0 + (ct << 4);
        const int cj = c >> 3;
        float4 o;
        #pragma unroll
        for (int jj = 0; jj < 4; jj++) {
            const int j = (jq << 2) + jj;
            ((float*)&o)[jj] = (float)S[(j << 9) + ((cj ^ (j & 7)) << 3) + (c & 7)];
        }
        *(float4*)(dst0 + ((size_t)c << 12)) = o;
    }
}

extern "C" void kernel_launch(void* const* d_in, const int* in_sizes, int n_in,
                              void* d_out, int out_size, void* d_ws, size_t ws_size,
                              hipStream_t stream)
{
    const float* x  = (const float*)d_in[0];
    const float* w1 = (const float*)d_in[1];
    const float* b1 = (const float*)d_in[2];
    const float* w2 = (const float*)d_in[3];
    const float* b2 = (const float*)d_in[4];
    float* x2d   = (float*)d_out;
    float* maskp = x2d + X2D_ELEMS;

    f16* chain = (f16*)d_ws;     // 72.3 MB
    f16* Wf    = (f16*)x2d;      // 31 MB scratch in x2d region, dead before assemble

    prep_k<<<(30 * 262144) / 256, 256, 0, stream>>>(w1, w2, Wf, maskp);

    // level 0: 16 per-layer kernels (co-split, barrier-free inner loop)
    conv_l0_first<<<512, 256, 0, stream>>>(x, Wf, b1, chain);
    int L = 64, cb = 64, prev = 0;
    for (int i = 0; i < 15; i++) {
        const f16* Wl = Wf + 262144 + (size_t)i * 524288;
        const float* bl = b2 + (size_t)i * C_;
        switch (L) {
            case 64: conv_l0<64><<<512, 256, 0, stream>>>(Wl, bl, chain, prev, cb); break;
            case 63: conv_l0<63><<<512, 256, 0, stream>>>(Wl, bl, chain, prev, cb); break;
            case 62: conv_l0<62><<<512, 256, 0, stream>>>(Wl, bl, chain, prev, cb); break;
            case 61: conv_l0<61><<<512, 256, 0, stream>>>(Wl, bl, chain, prev, cb); break;
            case 60: conv_l0<60><<<512, 256, 0, stream>>>(Wl, bl, chain, prev, cb); break;
            case 59: conv_l0<59><<<512, 256, 0, stream>>>(Wl, bl, chain, prev, cb); break;
            case 58: conv_l0<58><<<512, 256, 0, stream>>>(Wl, bl, chain, prev, cb); break;
            case 57: conv_l0<57><<<512, 256, 0, stream>>>(Wl, bl, chain, prev, cb); break;
            case 56: conv_l0<56><<<512, 256, 0, stream>>>(Wl, bl, chain, prev, cb); break;
            case 55: conv_l0<55><<<512, 256, 0, stream>>>(Wl, bl, chain, prev, cb); break;
            case 54: conv_l0<54><<<512, 256, 0, stream>>>(Wl, bl, chain, prev, cb); break;
            case 53: conv_l0<53><<<512, 256, 0, stream>>>(Wl, bl, chain, prev, cb); break;
            case 52: conv_l0<52><<<512, 256, 0, stream>>>(Wl, bl, chain, prev, cb); break;
            case 51: conv_l0<51><<<512, 256, 0, stream>>>(Wl, bl, chain, prev, cb); break;
            case 50: conv_l0<50><<<512, 256, 0, stream>>>(Wl, bl, chain, prev, cb); break;
        }
        prev = cb; cb += L - 1; L--;
    }
    // now L=49, prev=855, cb=904

    // level 1: pool(49->24) + 7 convs, one 512-thread kernel
    level_fused<49, 7, 2><<<64, 512, 0, stream>>>(
        Wf + 262144 + (size_t)15 * 524288, b2 + (size_t)15 * C_, chain, 855, 904);
    // level 2: pool(17->8) + 7 convs, one 512-thread kernel
    level_fused<17, 7, 1><<<64, 512, 0, stream>>>(
        Wf + 262144 + (size_t)22 * 524288, b2 + (size_t)22 * C_, chain, 1051, 1068);

    assemble_k<<<dim3(64, B_), 256, 0, stream>>>(chain, x2d);
}

// Round 10
// 659.320 us; speedup vs baseline: 4.6906x; 1.3258x over previous
//
#include <hip/hip_runtime.h>

typedef _Float16 f16;
typedef f16 f16x8 __attribute__((ext_vector_type(8)));
typedef f16 f16x4 __attribute__((ext_vector_type(4)));
typedef float f32x4 __attribute__((ext_vector_type(4)));

#define B_ 64
#define C_ 512
#define X2D_ELEMS ((size_t)134217728)  // 64*512*64*64
#define CHAIN_PITCH 1104               // chain: [b][col][512] f16

// (i,j) -> chain column, or -1
__device__ __forceinline__ int col_of(int i, int j) {
    const int d = j - i;
    if (d < 0) return -1;
    if (d <= 15) return 64 * d - (d * (d - 1)) / 2 + i;
    if (d >= 17 && d <= 31 && (d & 1) && !(i & 1)) {
        const int v = (d - 17) >> 1;
        return 904 + 24 * v - (v * (v - 1)) / 2 + (i >> 1);
    }
    if (d >= 35 && !((d - 35) & 3) && !(i & 3)) {
        const int v = (d - 35) >> 2;
        return 1068 + 8 * v - (v * (v - 1)) / 2 + (i >> 2);
    }
    return -1;
}

// ---------------------------------------------------------------------------
// co-sliced conv for layer 0 (proven R7-R9): block computes co [m0,m0+64)
// for all 64 cols of one b. S swizzled [rows][512 ci].
// ---------------------------------------------------------------------------
template<int K, int NF, int TAPS>
__device__ __forceinline__
void conv_split(const f16* S, const f16* __restrict__ wl,
                const float* __restrict__ bias, f16* __restrict__ chout,
                int Lin, int Lout, int m0)
{
    const int lane = threadIdx.x & 63, w = threadIdx.x >> 6;
    const int colq = lane & 15, kg = lane >> 4;
    const int mbase = m0 + w * 16;
    const f16* wp = wl + (size_t)(mbase + colq) * K + (kg << 3);

    int row[NF];
    #pragma unroll
    for (int nf = 0; nf < NF; nf++) {
        int c = nf * 16 + colq;
        if (c > Lin - TAPS) c = Lin - TAPS;
        row[nf] = c;
    }

    f32x4 acc[NF] = {};
    f16x8 a0 = *(const f16x8*)(wp);
    f16x8 a1 = *(const f16x8*)(wp + 32);
    f16x8 a2 = *(const f16x8*)(wp + 64);
    f16x8 a3 = *(const f16x8*)(wp + 96);

#define DO_STEP(AF, KK)                                                         \
    {                                                                           \
        const int t_ = (TAPS == 2 && (KK) >= 512) ? 1 : 0;                      \
        const int cch_ = (((KK) & 511) >> 3) + kg;                              \
        _Pragma("unroll")                                                       \
        for (int nf = 0; nf < NF; nf++) {                                       \
            const int r_ = row[nf] + t_;                                        \
            const f16x8 bf_ = *(const f16x8*)&S[(r_ << 9) + ((cch_ ^ (r_ & 7)) << 3)]; \
            acc[nf] = __builtin_amdgcn_mfma_f32_16x16x32_f16(AF, bf_, acc[nf], 0, 0, 0); \
        }                                                                       \
    }

    #pragma unroll
    for (int k0 = 0; k0 < K; k0 += 128) {
        DO_STEP(a0, k0);      if (k0 + 128 < K) a0 = *(const f16x8*)(wp + k0 + 128);
        DO_STEP(a1, k0 + 32); if (k0 + 128 < K) a1 = *(const f16x8*)(wp + k0 + 160);
        DO_STEP(a2, k0 + 64); if (k0 + 128 < K) a2 = *(const f16x8*)(wp + k0 + 192);
        DO_STEP(a3, k0 + 96); if (k0 + 128 < K) a3 = *(const f16x8*)(wp + k0 + 224);
    }
#undef DO_STEP

    const int co0 = mbase + (kg << 2);
    const float4 bb = *(const float4*)&bias[co0];
    #pragma unroll
    for (int nf = 0; nf < NF; nf++) {
        const int col = nf * 16 + colq;
        if (col < Lout) {
            f16x4 h;
            #pragma unroll
            for (int j = 0; j < 4; j++)
                h[j] = (f16)fmaxf(acc[nf][j] + ((const float*)&bb)[j], 0.0f);
            *(f16x4*)&chout[((size_t)col << 9) + co0] = h;
        }
    }
}

// layer 0: grid 512 = (b, q); stage fp32 x[b] transposed into LDS; k=1 conv
__global__ __launch_bounds__(256, 2)
void conv_l0_first(const float* __restrict__ x, const f16* __restrict__ Wf,
                   const float* __restrict__ b1, f16* __restrict__ chain)
{
    __shared__ __align__(16) f16 S[64 * 512];
    const int tid = threadIdx.x;
    const int b = blockIdx.x >> 3, q = blockIdx.x & 7;
    f16* chb = chain + (((size_t)b * CHAIN_PITCH) << 9);
    #pragma unroll 4
    for (int p = 0; p < 32; p++) {
        const int ci = p * 16 + (tid >> 4), l0 = (tid & 15) << 2;
        const float4 v = *(const float4*)&x[(((size_t)b * C_ + ci) << 6) + l0];
        #pragma unroll
        for (int j = 0; j < 4; j++) {
            const int r = l0 + j;
            S[(r << 9) + (((ci >> 3) ^ (r & 7)) << 3) + (ci & 7)] =
                (f16)((const float*)&v)[j];
        }
    }
    __syncthreads();
    conv_split<512, 4, 1>(S, Wf, b1, chb, 64, 64, q << 6);
}

// ---------------------------------------------------------------------------
// R4-proven conv-as-GEMM (k=2, K=1024, chain->chain). Block: 64 co x G
// batches. B staged once in swizzled LDS; barrier-free unroll-4 K loop.
// Grid axes SWAPPED vs R4: x = m-slice (8) so bid%8 = m -> per-XCD weight
// slice is L2-sticky; y = b-group (64/G).
// ---------------------------------------------------------------------------
__global__ __launch_bounds__(256, 2)
void conv_fused(const f16* __restrict__ xin, int cb_in,
                const f16* __restrict__ Wl, const float* __restrict__ bias,
                f16* __restrict__ chain, int cb_out,
                int Lin, int Lout, int G)
{
    constexpr int K = 1024;
    __shared__ f16 Bs[64 * 512];   // 64 KB
    const int tid = threadIdx.x, lane = tid & 63, wv = tid >> 6;
    const int b0 = blockIdx.y * G, m0 = blockIdx.x * 64;
    const int rows = G * Lin;

    // stage input rows once: row r = input[b0 + r/Lin][cb_in + r%Lin][*]
    for (int r = wv; r < rows; r += 4) {
        const int g = r / Lin, l = r - g * Lin;
        const f16* src = xin + (((size_t)(b0 + g) * CHAIN_PITCH + cb_in + l) << 9);
        const f16x8 v = *(const f16x8*)(src + (lane << 3));
        *(f16x8*)&Bs[(r << 9) + ((lane ^ (r & 7)) << 3)] = v;
    }

    // per-thread n mapping (n = nf*16 + lane&15 -> batch g, position l)
    int vg[4], vl[4], row0[4]; bool val[4];
    #pragma unroll
    for (int nf = 0; nf < 4; nf++) {
        const int v = nf * 16 + (lane & 15);
        vg[nf] = v / Lout; vl[nf] = v - vg[nf] * Lout;
        val[nf] = vg[nf] < G;
        row0[nf] = val[nf] ? vg[nf] * Lin + vl[nf] : 0;
    }
    const int kg = lane >> 4;
    const f16* wp = Wl + (size_t)(m0 + wv * 16 + (lane & 15)) * K + (kg << 3);

    __syncthreads();

    // barrier-free K loop (R4-proven; compiler pipelines the unroll-4)
    f32x4 acc[4] = {};
    #pragma unroll 4
    for (int k0 = 0; k0 < K; k0 += 32) {
        const f16x8 af = *(const f16x8*)(wp + k0);
        const int t = (k0 >= 512) ? 1 : 0;
        const int cchunk = ((k0 & 511) >> 3) + kg;
        #pragma unroll
        for (int nf = 0; nf < 4; nf++) {
            const int r = row0[nf] + t;
            const f16x8 bf = *(const f16x8*)&Bs[(r << 9) + ((cchunk ^ (r & 7)) << 3)];
            acc[nf] = __builtin_amdgcn_mfma_f32_16x16x32_f16(af, bf, acc[nf], 0, 0, 0);
        }
    }

    // epilogue: bias + relu, 8 B packed stores into chain
    const int co0 = m0 + wv * 16 + ((lane >> 4) << 2);
    const float4 bb = *(const float4*)&bias[co0];
    #pragma unroll
    for (int nf = 0; nf < 4; nf++) {
        if (!val[nf]) continue;
        f16x4 h;
        #pragma unroll
        for (int j = 0; j < 4; j++)
            h[j] = (f16)fmaxf(acc[nf][j] + ((const float*)&bb)[j], 0.0f);
        *(f16x4*)&chain[(((size_t)(b0 + vg[nf]) * CHAIN_PITCH + cb_out + vl[nf]) << 9) + co0] = h;
    }
}

// MaxPool1d(k=3,s=2) + relu, chain->chain (R4-proven)
__global__ void maxpool2(f16* __restrict__ chain, int cb_in, int cb_out)
{
    const int l = blockIdx.x, b = blockIdx.y, tid = threadIdx.x;
    const f16* s = chain + (((size_t)b * CHAIN_PITCH + cb_in + 2 * l) << 9) + 2 * tid;
    f16 o0 = (f16)fmaxf(fmaxf(fmaxf((float)s[0], (float)s[512]), (float)s[1024]), 0.0f);
    f16 o1 = (f16)fmaxf(fmaxf(fmaxf((float)s[1], (float)s[513]), (float)s[1025]), 0.0f);
    f16* d = &chain[(((size_t)b * CHAIN_PITCH + cb_out + l) << 9) + 2 * tid];
    d[0] = o0; d[1] = o1;
}

// prep: mask + weights fp32 -> f16 [co][t*512+ci] (one kernel)
__global__ void prep_all(const float* __restrict__ w1, const float* __restrict__ w2,
                         f16* __restrict__ Wf, float* __restrict__ maskp)
{
    const unsigned idx = blockIdx.x * 256 + threadIdx.x;
    if (idx < 4096u)
        maskp[idx] = (col_of(idx >> 6, idx & 63) >= 0) ? 1.0f : 0.0f;
    if (idx < 262144u) {
        Wf[idx] = (f16)w1[idx];
    } else if (idx < 30u * 262144u) {
        const unsigned r = idx - 262144u;
        const int k2 = r >> 18;
        const unsigned rem = r & 262143u;
        const int co = rem >> 9, ci = rem & 511;
        const float2 v = *(const float2*)&w2[((((size_t)k2 << 9) + co) << 10) + (ci << 1)];
        f16* base = Wf + 262144 + ((size_t)k2 << 19) + ((size_t)co << 10);
        base[ci] = (f16)v.x;
        base[512 + ci] = (f16)v.y;
    }
}

// assemble (R4-proven): block=(i, b); swizzled LDS stage; coalesced x2d write
__global__ __launch_bounds__(256)
void assemble3(const f16* __restrict__ chain, float* __restrict__ x2d)
{
    __shared__ __align__(16) f16 J[64 * 512];
    const int tid = threadIdx.x, lane = tid & 63, wv = tid >> 6;
    const int i = blockIdx.x, b = blockIdx.y;

    for (int j = wv; j < 64; j += 4) {
        const int col = col_of(i, j);
        f16x8 v = {0, 0, 0, 0, 0, 0, 0, 0};
        if (col >= 0)
            v = *(const f16x8*)(chain + (((size_t)b * CHAIN_PITCH + col) << 9) + (lane << 3));
        *(f16x8*)&J[(j << 9) + ((lane ^ (j & 7)) << 3)] = v;
    }
    __syncthreads();

    const int jq = tid & 15, c0 = tid >> 4;
    float* dst0 = x2d + (((size_t)b * C_) << 12) + (i << 6) + (jq << 2);
    for (int ct = 0; ct < 32; ct++) {
        const int c = c0 + (ct << 4);
        const int cj = c >> 3;
        float4 o;
        #pragma unroll
        for (int jj = 0; jj < 4; jj++) {
            const int j = (jq << 2) + jj;
            ((float*)&o)[jj] = (float)J[(j << 9) + ((cj ^ (j & 7)) << 3) + (c & 7)];
        }
        *(float4*)(dst0 + ((size_t)c << 12)) = o;
    }
}

extern "C" void kernel_launch(void* const* d_in, const int* in_sizes, int n_in,
                              void* d_out, int out_size, void* d_ws, size_t ws_size,
                              hipStream_t stream)
{
    const float* x  = (const float*)d_in[0];
    const float* w1 = (const float*)d_in[1];
    const float* b1 = (const float*)d_in[2];
    const float* w2 = (const float*)d_in[3];
    const float* b2 = (const float*)d_in[4];
    float* x2d   = (float*)d_out;
    float* maskp = x2d + X2D_ELEMS;

    // chain (72.3 MB) in d_ws; f16 weights (31 MB) in the x2d region —
    // fully overwritten by assemble3 after weights are dead.
    f16* chain = (f16*)d_ws;
    f16* Wf    = (f16*)x2d;

    prep_all<<<(30 * 262144) / 256, 256, 0, stream>>>(w1, w2, Wf, maskp);

    // layer 0: k=1 conv from fp32 x (in-LDS transpose staging)
    conv_l0_first<<<512, 256, 0, stream>>>(x, Wf, b1, chain);

    const int counts[3] = {16, 8, 8};
    int L = 64, k2 = 0, cb = 64, prev = 0;
    for (int level = 0; level < 3; level++) {
        for (int order = 0; order < counts[level]; order++) {
            if (level == 0 && order == 0) continue;   // done above
            if (level > 0 && order == 0) {
                const int Lp = (L - 3) / 2 + 1;
                maxpool2<<<dim3(Lp, B_), 256, 0, stream>>>(chain, prev, cb);
                prev = cb; cb += Lp; L = Lp;
            } else {
                const int Lout = L - 1;
                int G = 1;
                while ((G * 2) * Lout <= 64 && (G * 2) * L <= 64) G *= 2;
                conv_fused<<<dim3(8, 64 / G), 256, 0, stream>>>(
                    chain, prev, Wf + 262144 + (size_t)k2 * 524288,
                    b2 + (size_t)k2 * C_, chain, cb, L, Lout, G);
                k2++; prev = cb; cb += Lout; L = Lout;
            }
        }
    }

    assemble3<<<dim3(64, B_), 256, 0, stream>>>(chain, x2d);
}